// Round 12
// baseline (277.558 us; speedup 1.0000x reference)
//
#include <hip/hip_runtime.h>

typedef __bf16 bf16;
typedef __bf16 bf16x8 __attribute__((ext_vector_type(8)));
typedef __bf16 bf16x4 __attribute__((ext_vector_type(4)));
typedef float f32x4 __attribute__((ext_vector_type(4)));
typedef unsigned int uint;
typedef unsigned short ushort;

typedef const __attribute__((address_space(1))) void* gas_ptr;
typedef __attribute__((address_space(3))) void* las_ptr;

__device__ __forceinline__ void load16_lds(const void* g, void* l) {
  __builtin_amdgcn_global_load_lds((gas_ptr)g, (las_ptr)l, 16, 0, 0);
}

// ---------------------------------------------------------------------------
// x fp32 -> bf16 cast (8 elems/thread)
// ---------------------------------------------------------------------------
__global__ __launch_bounds__(256) void cast_f32_bf16(
    const float* __restrict__ in, bf16* __restrict__ out) {
  size_t i = (size_t)blockIdx.x * 256 + threadIdx.x;
  const float4* p = reinterpret_cast<const float4*>(in) + i * 2;
  float4 a = p[0], b = p[1];
  bf16x8 v;
  v[0] = (bf16)a.x; v[1] = (bf16)a.y; v[2] = (bf16)a.z; v[3] = (bf16)a.w;
  v[4] = (bf16)b.x; v[5] = (bf16)b.y; v[6] = (bf16)b.z; v[7] = (bf16)b.w;
  reinterpret_cast<bf16x8*>(out)[i] = v;
}

// ---------------------------------------------------------------------------
// Weight transpose + cast: in [K][N] fp32 -> out [N][K] bf16, 64x64 tiles
// ---------------------------------------------------------------------------
__global__ __launch_bounds__(256) void transpose_f32_bf16(
    const float* __restrict__ in, bf16* __restrict__ out, int K, int N) {
  __shared__ __attribute__((aligned(16))) bf16 tile[64 * 72];
  const int k0 = blockIdx.y * 64, n0 = blockIdx.x * 64;
  const int tid = threadIdx.x;
  for (int c = tid; c < 1024; c += 256) {
    int ki = c >> 4, j4 = c & 15;
    float4 f = *reinterpret_cast<const float4*>(in + (size_t)(k0 + ki) * N + n0 + j4 * 4);
    bf16* t = &tile[ki * 72 + j4 * 4];
    t[0] = (bf16)f.x; t[1] = (bf16)f.y; t[2] = (bf16)f.z; t[3] = (bf16)f.w;
  }
  __syncthreads();
  for (int c = tid; c < 512; c += 256) {
    int ni = c >> 3, k8 = c & 7;
    bf16x8 v;
    for (int j = 0; j < 8; j++) v[j] = tile[(k8 * 8 + j) * 72 + ni];
    *reinterpret_cast<bf16x8*>(out + (size_t)(n0 + ni) * K + k0 + k8 * 8) = v;
  }
}

// ---------------------------------------------------------------------------
// GEMM: C[M,N] = A[M,K] * Bt[N,K]^T  (bf16 in, f32 accum, CT out)
// 128x128 tile, BK=64. Staging via global_load_lds width=16. (R4-exact.)
// XCD-aware bijective block swizzle (nwg % 8 == 0 by launcher).
// LDS chunk layout: 16B chunk p holds logical (row=p>>3, kc=(p&7)^(row&7)).
// ---------------------------------------------------------------------------
template <typename CT>
__global__ __launch_bounds__(256, 2) void gemm_lds(
    const bf16* __restrict__ A, const bf16* __restrict__ Bt,
    CT* __restrict__ C, int M, int N, int K) {
  __shared__ __attribute__((aligned(16))) bf16 As[128 * 64];
  __shared__ __attribute__((aligned(16))) bf16 Bs[128 * 64];
  const int tid = threadIdx.x;
  const int wave = tid >> 6;
  const int lane = tid & 63;
  const int l15 = lane & 15;
  const int quad = lane >> 4;
  const int nwg = gridDim.x * gridDim.y;
  const int orig = blockIdx.y * gridDim.x + blockIdx.x;
  const int swz = (orig & 7) * (nwg >> 3) + (orig >> 3);
  const int m0 = (swz / gridDim.x) * 128;
  const int n0 = (swz % gridDim.x) * 128;
  const int wm = (wave >> 1) * 64;
  const int wn = (wave & 1) * 64;

  f32x4 acc[4][4] = {};

  for (int kt = 0; kt < K; kt += 64) {
    __syncthreads();
    for (int it = 0; it < 4; ++it) {
      int p = it * 256 + wave * 64 + lane;
      int row = p >> 3, kc = (p & 7) ^ (row & 7);
      load16_lds(A + (size_t)(m0 + row) * K + kt + kc * 8, &As[p * 8]);
      load16_lds(Bt + (size_t)(n0 + row) * K + kt + kc * 8, &Bs[p * 8]);
    }
    __syncthreads();
    for (int kk = 0; kk < 64; kk += 32) {
      const int kc = (kk >> 3) + quad;
      bf16x8 af[4], bfr[4];
      for (int i = 0; i < 4; i++) {
        int row = wm + i * 16 + l15;
        af[i] = *reinterpret_cast<const bf16x8*>(&As[(row * 8 + (kc ^ (row & 7))) * 8]);
      }
      for (int j = 0; j < 4; j++) {
        int row = wn + j * 16 + l15;
        bfr[j] = *reinterpret_cast<const bf16x8*>(&Bs[(row * 8 + (kc ^ (row & 7))) * 8]);
      }
      for (int i = 0; i < 4; i++)
        for (int j = 0; j < 4; j++)
          acc[i][j] = __builtin_amdgcn_mfma_f32_16x16x32_bf16(af[i], bfr[j], acc[i][j], 0, 0, 0);
    }
  }

  for (int i = 0; i < 4; i++)
    for (int j = 0; j < 4; j++)
      for (int r = 0; r < 4; r++) {
        int row = m0 + wm + i * 16 + quad * 4 + r;
        int col = n0 + wn + j * 16 + l15;
        C[(size_t)row * N + col] = (CT)acc[i][j][r];
      }
}

// ---------------------------------------------------------------------------
// Flash attention, swapped-QK^T (R10 compute path + R5-verified staging):
//  - K staged by global_load_lds DMA, 1 chunk/thread; per-lane global source
//    pre-composed with inverse-rho + XOR-chunk so LDS bytes are identical to
//    the HW-verified layout. Zero VALU, no K prefetch regs.
//  - V staged by ALL 8 waves (4 dword-packs/thread) into swizzled Vs.
//  - QK accumulator seeded with nm = broadcast(-m) (MFMA emits s-m directly).
//  - defer-max: common path tests only the lane-local max (__all(mt<=8));
//    cross-lane shfl reduce + rescale in the rare branch; monotone-m clamp.
// Grid (B*H=64, T/128=16); 8 waves x 16 q-rows; K/V dbuf, 1 barrier/tile.
// ---------------------------------------------------------------------------
__device__ __forceinline__ int vs_dw(int d, int kdw) {
  return d * 32 + (kdw ^ ((((d >> 3) ^ d) & 7) * 4));
}

__global__ __launch_bounds__(512, 4) void attn_kernel(
    const bf16* __restrict__ qkv, bf16* __restrict__ out) {
  __shared__ __attribute__((aligned(16))) bf16 Ks[2][64 * 64];  // XOR-chunk, rho-rows
  __shared__ __attribute__((aligned(16))) uint Vs[2][64 * 32];  // swizzled [d][keypair]

  const int tid = threadIdx.x;
  const int wave = tid >> 6;    // 0..7
  const int lane = tid & 63;
  const int l15 = lane & 15;
  const int quad = lane >> 4;
  const int b = blockIdx.x >> 4;
  const int h = blockIdx.x & 15;
  const int qt0 = blockIdx.y * 128;
  const bf16* base = qkv + (size_t)b * 2048 * 3072 + h * 64;
  const float L2E = 1.44269504f;

  // Q fragments (B-operand), pre-scaled by log2(e)
  bf16x8 aq0, aq1;
  {
    const bf16* qrow = base + (size_t)(qt0 + wave * 16 + l15) * 3072;
    aq0 = *reinterpret_cast<const bf16x8*>(qrow + quad * 8);
    aq1 = *reinterpret_cast<const bf16x8*>(qrow + 32 + quad * 8);
    for (int j = 0; j < 8; j++) {
      aq0[j] = (bf16)((float)aq0[j] * L2E);
      aq1[j] = (bf16)((float)aq1[j] * L2E);
    }
  }

  // ones-column B fragment: B[k][0] = 1 -> lanes with l15==0 hold 1s
  bf16x8 bones = {};
  if (l15 == 0)
    for (int j = 0; j < 8; j++) bones[j] = (bf16)1.0f;

  // nm = broadcast(-m) used as QK MFMA C-in; m starts at 0 (first tile
  // takes the rescale branch). All 4 C-slots are the same query l15.
  f32x4 nm = {};
  f32x4 o[4] = {};
  f32x4 l_acc = {};

  // ---- K staging: global_load_lds, 1 chunk (16B) per thread ----
  // LDS chunk c holds (lds_row = c>>3, kc = (c&7)^(row&7)); lds_row r holds
  // true key inv_rho(r): k2=r4, k4=r3, k3=r2, k1:0=r1:0, k5=r5.
  const int c = tid;                 // 0..511
  const int krow = c >> 3;
  const int kc8 = (c & 7) ^ (krow & 7);
  const int ktrue = (((krow >> 4) & 1) << 2) | (((krow >> 3) & 1) << 4) |
                    (((krow >> 2) & 1) << 3) | (krow & 3) | (krow & 32);
  const bf16* kgp = base + 1024 + (size_t)ktrue * 3072 + kc8 * 8;

  // ---- V staging: 4 dword-packs per thread (all 8 waves) ----
  const int vkp = tid >> 4;          // keypair 0..31
  const int vd0 = (tid & 15) * 4;    // d base 0..60
  const bf16* vgp = base + (size_t)(2 * vkp) * 3072 + 2048 + vd0;

  // ---- prologue: tile 0 ----
  load16_lds(kgp, &Ks[0][c * 8]);
  bf16x4 vpre0 = *reinterpret_cast<const bf16x4*>(vgp);
  bf16x4 vpre1 = *reinterpret_cast<const bf16x4*>(vgp + 3072);

  for (int kt = 0; kt < 2048; kt += 64) {
    const int cur = (kt >> 6) & 1;
    // ---- write prefetched V (tile t) into Vs[cur] ----
    {
      const ushort* u0 = reinterpret_cast<const ushort*>(&vpre0);
      const ushort* u1 = reinterpret_cast<const ushort*>(&vpre1);
      for (int i = 0; i < 4; i++)
        Vs[cur][vs_dw(vd0 + i, vkp)] = (uint)u0[i] | ((uint)u1[i] << 16);
    }
    __syncthreads();   // V visible; K DMA (issued last iter) drained

    // ---- issue next-tile staging; latency hides under compute ----
    if (kt + 64 < 2048) {
      const size_t off = (size_t)(kt + 64) * 3072;
      load16_lds(kgp + off, &Ks[cur ^ 1][c * 8]);
      vpre0 = *reinterpret_cast<const bf16x4*>(vgp + off);
      vpre1 = *reinterpret_cast<const bf16x4*>(vgp + off + 3072);
    }

    // ---- S - m = K (Q*log2e)^T + nm : mfma with C-in = nm ----
    f32x4 s[4];
    __builtin_amdgcn_s_setprio(1);
    for (int n = 0; n < 4; n++) {
      int row = n * 16 + l15;
      int xr = row & 7;
      bf16x8 ak0 = *reinterpret_cast<const bf16x8*>(&Ks[cur][(row * 8 + (quad ^ xr)) * 8]);
      bf16x8 ak1 = *reinterpret_cast<const bf16x8*>(&Ks[cur][(row * 8 + ((4 + quad) ^ xr)) * 8]);
      f32x4 z = __builtin_amdgcn_mfma_f32_16x16x32_bf16(ak0, aq0, nm, 0, 0, 0);
      z = __builtin_amdgcn_mfma_f32_16x16x32_bf16(ak1, aq1, z, 0, 0, 0);
      s[n] = z;
    }
    __builtin_amdgcn_s_setprio(0);

    // ---- per-query online softmax on relative scores (s already - m) ----
    float mt = fmaxf(fmaxf(s[0][0], s[0][1]), s[0][2]);
    mt = fmaxf(fmaxf(mt, s[0][3]), s[1][0]);
    mt = fmaxf(fmaxf(mt, s[1][1]), s[1][2]);
    mt = fmaxf(fmaxf(mt, s[1][3]), s[2][0]);
    mt = fmaxf(fmaxf(mt, s[2][1]), s[2][2]);
    mt = fmaxf(fmaxf(mt, s[2][3]), s[3][0]);
    mt = fmaxf(fmaxf(mt, s[3][1]), s[3][2]);
    mt = fmaxf(mt, s[3][3]);

    // defer-max: rescale only when some lane's local max grew past +8.
    // (global_max <= m+8 iff ALL lanes' local relative maxes <= 8.)
    if (!__all(mt <= 8.0f)) {
      mt = fmaxf(mt, __shfl_xor(mt, 16, 64));
      mt = fmaxf(mt, __shfl_xor(mt, 32, 64));   // global relative max for l15
      mt = fmaxf(mt, 0.0f);                     // monotone m: shift >= 0
      float alpha = __builtin_amdgcn_exp2f(-mt);  // <= 1
      float v = nm[0] - mt;                      // new -m (replicated)
      nm[0] = v; nm[1] = v; nm[2] = v; nm[3] = v;
      float a0 = __shfl(alpha, quad * 4 + 0, 64);
      float a1 = __shfl(alpha, quad * 4 + 1, 64);
      float a2 = __shfl(alpha, quad * 4 + 2, 64);
      float a3 = __shfl(alpha, quad * 4 + 3, 64);
      l_acc[0] *= a0; l_acc[1] *= a1; l_acc[2] *= a2; l_acc[3] *= a3;
      for (int n = 0; n < 4; n++) {
        o[n][0] *= a0; o[n][1] *= a1; o[n][2] *= a2; o[n][3] *= a3;
      }
      for (int n = 0; n < 4; n++)
        for (int r = 0; r < 4; r++) s[n][r] -= mt;   // shift to new m
    }

    // P in PV A-fragment order directly (rho-permuted K rows); s is relative
    bf16x8 ap0, ap1;
    for (int r = 0; r < 4; r++) {
      ap0[r]     = (bf16)__builtin_amdgcn_exp2f(s[0][r]);
      ap0[4 + r] = (bf16)__builtin_amdgcn_exp2f(s[1][r]);
      ap1[r]     = (bf16)__builtin_amdgcn_exp2f(s[2][r]);
      ap1[4 + r] = (bf16)__builtin_amdgcn_exp2f(s[3][r]);
    }

    __builtin_amdgcn_s_setprio(1);
    // row-sum via ones-column (C-layout rows = queries quad*4+r)
    l_acc = __builtin_amdgcn_mfma_f32_16x16x32_bf16(ap0, bones, l_acc, 0, 0, 0);
    l_acc = __builtin_amdgcn_mfma_f32_16x16x32_bf16(ap1, bones, l_acc, 0, 0, 0);

    // O += P V  (V fragments from swizzled Vs)
    for (int n = 0; n < 4; n++) {
      int d = n * 16 + l15;
      uint4 u0 = *reinterpret_cast<const uint4*>(&Vs[cur][vs_dw(d, quad * 4)]);
      uint4 u1 = *reinterpret_cast<const uint4*>(&Vs[cur][vs_dw(d, 16 + quad * 4)]);
      bf16x8 bv0 = *reinterpret_cast<const bf16x8*>(&u0);
      bf16x8 bv1 = *reinterpret_cast<const bf16x8*>(&u1);
      o[n] = __builtin_amdgcn_mfma_f32_16x16x32_bf16(ap0, bv0, o[n], 0, 0, 0);
      o[n] = __builtin_amdgcn_mfma_f32_16x16x32_bf16(ap1, bv1, o[n], 0, 0, 0);
    }
    __builtin_amdgcn_s_setprio(0);
  }

  for (int r = 0; r < 4; r++) {
    float lv = __shfl(l_acc[r], quad * 16, 64);
    float inv = 1.0f / lv;
    int q = qt0 + wave * 16 + quad * 4 + r;
    bf16* orow = out + (size_t)(b * 2048 + q) * 1024 + h * 64;
    for (int n = 0; n < 4; n++) orow[n * 16 + l15] = (bf16)(o[n][r] * inv);
  }
}

// ---------------------------------------------------------------------------
// Launch
// ---------------------------------------------------------------------------
extern "C" void kernel_launch(void* const* d_in, const int* in_sizes, int n_in,
                              void* d_out, int out_size, void* d_ws, size_t ws_size,
                              hipStream_t stream) {
  const float* x = (const float*)d_in[0];       // [8192, 1024] fp32
  const float* w_qkv = (const float*)d_in[1];   // [1024, 3072] fp32
  const float* w_proj = (const float*)d_in[2];  // [1024, 1024] fp32
  float* out = (float*)d_out;                   // [8192, 1024] fp32

  bf16* ws = (bf16*)d_ws;
  bf16* x_bf = ws;                                   // [8192,1024]
  bf16* wqkvT = x_bf + (size_t)8192 * 1024;          // [3072,1024]
  bf16* wprojT = wqkvT + 3072 * 1024;                // [1024,1024]
  bf16* qkv = wprojT + 1024 * 1024;                  // [8192,3072]
  bf16* attn_out = qkv + (size_t)8192 * 3072;        // [8192,1024]

  cast_f32_bf16<<<4096, 256, 0, stream>>>(x, x_bf);
  transpose_f32_bf16<<<dim3(48, 16), 256, 0, stream>>>(w_qkv, wqkvT, 1024, 3072);
  transpose_f32_bf16<<<dim3(16, 16), 256, 0, stream>>>(w_proj, wprojT, 1024, 1024);
  gemm_lds<bf16><<<dim3(24, 64), 256, 0, stream>>>(x_bf, wqkvT, qkv, 8192, 3072, 1024);
  attn_kernel<<<dim3(64, 16), 512, 0, stream>>>(qkv, attn_out);
  gemm_lds<float><<<dim3(8, 64), 256, 0, stream>>>(attn_out, wprojT, out, 8192, 1024, 1024);
}

// Round 16
// 259.039 us; speedup vs baseline: 1.0715x; 1.0715x over previous
//
#include <hip/hip_runtime.h>

typedef __bf16 bf16;
typedef __bf16 bf16x8 __attribute__((ext_vector_type(8)));
typedef float f32x4 __attribute__((ext_vector_type(4)));
typedef unsigned int uint;
typedef unsigned short ushort;

typedef const __attribute__((address_space(1))) void* gas_ptr;
typedef __attribute__((address_space(3))) void* las_ptr;

__device__ __forceinline__ void load16_lds(const void* g, void* l) {
  __builtin_amdgcn_global_load_lds((gas_ptr)g, (las_ptr)l, 16, 0, 0);
}

// ---------------------------------------------------------------------------
// x fp32 -> bf16 cast (8 elems/thread)
// ---------------------------------------------------------------------------
__global__ __launch_bounds__(256) void cast_f32_bf16(
    const float* __restrict__ in, bf16* __restrict__ out) {
  size_t i = (size_t)blockIdx.x * 256 + threadIdx.x;
  const float4* p = reinterpret_cast<const float4*>(in) + i * 2;
  float4 a = p[0], b = p[1];
  bf16x8 v;
  v[0] = (bf16)a.x; v[1] = (bf16)a.y; v[2] = (bf16)a.z; v[3] = (bf16)a.w;
  v[4] = (bf16)b.x; v[5] = (bf16)b.y; v[6] = (bf16)b.z; v[7] = (bf16)b.w;
  reinterpret_cast<bf16x8*>(out)[i] = v;
}

// ---------------------------------------------------------------------------
// Weight transpose + cast: in [K][N] fp32 -> out [N][K] bf16, 64x64 tiles
// ---------------------------------------------------------------------------
__global__ __launch_bounds__(256) void transpose_f32_bf16(
    const float* __restrict__ in, bf16* __restrict__ out, int K, int N) {
  __shared__ __attribute__((aligned(16))) bf16 tile[64 * 72];
  const int k0 = blockIdx.y * 64, n0 = blockIdx.x * 64;
  const int tid = threadIdx.x;
  for (int c = tid; c < 1024; c += 256) {
    int ki = c >> 4, j4 = c & 15;
    float4 f = *reinterpret_cast<const float4*>(in + (size_t)(k0 + ki) * N + n0 + j4 * 4);
    bf16* t = &tile[ki * 72 + j4 * 4];
    t[0] = (bf16)f.x; t[1] = (bf16)f.y; t[2] = (bf16)f.z; t[3] = (bf16)f.w;
  }
  __syncthreads();
  for (int c = tid; c < 512; c += 256) {
    int ni = c >> 3, k8 = c & 7;
    bf16x8 v;
    for (int j = 0; j < 8; j++) v[j] = tile[(k8 * 8 + j) * 72 + ni];
    *reinterpret_cast<bf16x8*>(out + (size_t)(n0 + ni) * K + k0 + k8 * 8) = v;
  }
}

// ---------------------------------------------------------------------------
// GEMM: C[M,N] = A[M,K] * Bt[N,K]^T  (bf16 in, f32 accum, CT out)
// 128x128 tile, BK=64. Staging via global_load_lds width=16.
// XCD-aware bijective block swizzle (nwg % 8 == 0 by launcher).
// LDS chunk layout: 16B chunk p holds logical (row=p>>3, kc=(p&7)^(row&7)).
// ---------------------------------------------------------------------------
template <typename CT>
__global__ __launch_bounds__(256, 2) void gemm_lds(
    const bf16* __restrict__ A, const bf16* __restrict__ Bt,
    CT* __restrict__ C, int M, int N, int K) {
  __shared__ __attribute__((aligned(16))) bf16 As[128 * 64];
  __shared__ __attribute__((aligned(16))) bf16 Bs[128 * 64];
  const int tid = threadIdx.x;
  const int wave = tid >> 6;
  const int lane = tid & 63;
  const int l15 = lane & 15;
  const int quad = lane >> 4;
  const int nwg = gridDim.x * gridDim.y;
  const int orig = blockIdx.y * gridDim.x + blockIdx.x;
  const int swz = (orig & 7) * (nwg >> 3) + (orig >> 3);
  const int m0 = (swz / gridDim.x) * 128;
  const int n0 = (swz % gridDim.x) * 128;
  const int wm = (wave >> 1) * 64;
  const int wn = (wave & 1) * 64;

  f32x4 acc[4][4] = {};

  for (int kt = 0; kt < K; kt += 64) {
    __syncthreads();
    for (int it = 0; it < 4; ++it) {
      int p = it * 256 + wave * 64 + lane;
      int row = p >> 3, kc = (p & 7) ^ (row & 7);
      load16_lds(A + (size_t)(m0 + row) * K + kt + kc * 8, &As[p * 8]);
      load16_lds(Bt + (size_t)(n0 + row) * K + kt + kc * 8, &Bs[p * 8]);
    }
    __syncthreads();
    for (int kk = 0; kk < 64; kk += 32) {
      const int kc = (kk >> 3) + quad;
      bf16x8 af[4], bfr[4];
      for (int i = 0; i < 4; i++) {
        int row = wm + i * 16 + l15;
        af[i] = *reinterpret_cast<const bf16x8*>(&As[(row * 8 + (kc ^ (row & 7))) * 8]);
      }
      for (int j = 0; j < 4; j++) {
        int row = wn + j * 16 + l15;
        bfr[j] = *reinterpret_cast<const bf16x8*>(&Bs[(row * 8 + (kc ^ (row & 7))) * 8]);
      }
      for (int i = 0; i < 4; i++)
        for (int j = 0; j < 4; j++)
          acc[i][j] = __builtin_amdgcn_mfma_f32_16x16x32_bf16(af[i], bfr[j], acc[i][j], 0, 0, 0);
    }
  }

  for (int i = 0; i < 4; i++)
    for (int j = 0; j < 4; j++)
      for (int r = 0; r < 4; r++) {
        int row = m0 + wm + i * 16 + quad * 4 + r;
        int col = n0 + wn + j * 16 + l15;
        C[(size_t)row * N + col] = (CT)acc[i][j][r];
      }
}

// ---------------------------------------------------------------------------
// Flash attention, swapped-QK^T (best verified: R10, attn 101.7 us):
//  - R4 staging: waves 0-3 stage V (8 dword-packs), waves 4-7 stage K via
//    reg prefetch into rho-permuted XOR-chunk LDS; dbuf, 1 barrier/tile.
//  - QK accumulator seeded with nm = broadcast(-m): MFMA emits s-m directly.
//  - defer-max: common path tests only the lane-local max (__all(mt<=8));
//    cross-lane shfl reduce + rescale in the rare branch; monotone-m clamp.
// Grid (B*H=64, T/128=16); 8 waves x 16 q-rows.
// ---------------------------------------------------------------------------
__device__ __forceinline__ int vs_dw(int d, int kdw) {
  return d * 32 + (kdw ^ ((((d >> 3) ^ d) & 7) * 4));
}

__global__ __launch_bounds__(512, 4) void attn_kernel(
    const bf16* __restrict__ qkv, bf16* __restrict__ out) {
  __shared__ __attribute__((aligned(16))) bf16 Ks[2][64 * 64];  // XOR-chunk, rho-rows
  __shared__ __attribute__((aligned(16))) uint Vs[2][64 * 32];  // swizzled [d][keypair]

  const int tid = threadIdx.x;
  const int wave = tid >> 6;    // 0..7
  const int lane = tid & 63;
  const int l15 = lane & 15;
  const int quad = lane >> 4;
  const int b = blockIdx.x >> 4;
  const int h = blockIdx.x & 15;
  const int qt0 = blockIdx.y * 128;
  const bf16* base = qkv + (size_t)b * 2048 * 3072 + h * 64;
  const float L2E = 1.44269504f;

  // Q fragments (B-operand), pre-scaled by log2(e)
  bf16x8 aq0, aq1;
  {
    const bf16* qrow = base + (size_t)(qt0 + wave * 16 + l15) * 3072;
    aq0 = *reinterpret_cast<const bf16x8*>(qrow + quad * 8);
    aq1 = *reinterpret_cast<const bf16x8*>(qrow + 32 + quad * 8);
    for (int j = 0; j < 8; j++) {
      aq0[j] = (bf16)((float)aq0[j] * L2E);
      aq1[j] = (bf16)((float)aq1[j] * L2E);
    }
  }

  // ones-column B fragment: B[k][0] = 1 -> lanes with l15==0 hold 1s
  bf16x8 bones = {};
  if (l15 == 0)
    for (int j = 0; j < 8; j++) bones[j] = (bf16)1.0f;

  // nm = broadcast(-m) used as QK MFMA C-in; m starts at 0 (first tile
  // takes the rescale branch). All 4 C-slots are the same query l15.
  f32x4 nm = {};
  f32x4 o[4] = {};
  f32x4 l_acc = {};

  // staging role: waves 0-3 stage V, waves 4-7 stage K
  const int t2 = tid & 255;
  const int kp = t2 >> 3;    // V: key pair 0..31 / K: key row 0..31 (and +32)
  const int oct = t2 & 7;    // d octet / d chunk
  const bool vrole = (wave < 4);
  // K staging dest (rho-permuted rows, XOR chunks)
  const int prow = ((kp & 4) << 2) | ((kp & 24) >> 1) | (kp & 3);
  const int kxor = oct ^ (prow & 7);
  const int kdst0 = (prow * 8 + kxor) * 8;
  const int kdst1 = kdst0 + 32 * 64;

  // ---- prologue: prefetch KV tile 0 into registers (role-split) ----
  bf16x8 pre0, pre1;
  if (vrole) {
    const bf16* v0p = base + (size_t)(2 * kp) * 3072 + 2048 + oct * 8;
    pre0 = *reinterpret_cast<const bf16x8*>(v0p);
    pre1 = *reinterpret_cast<const bf16x8*>(v0p + 3072);
  } else {
    const bf16* kb = base + 1024 + (size_t)kp * 3072 + oct * 8;
    pre0 = *reinterpret_cast<const bf16x8*>(kb);
    pre1 = *reinterpret_cast<const bf16x8*>(kb + (size_t)32 * 3072);
  }

  for (int kt = 0; kt < 2048; kt += 64) {
    const int cur = (kt >> 6) & 1;
    // ---- write prefetched tile t into buf[cur] ----
    if (vrole) {
      const ushort* u0 = reinterpret_cast<const ushort*>(&pre0);
      const ushort* u1 = reinterpret_cast<const ushort*>(&pre1);
      for (int i = 0; i < 8; i++)
        Vs[cur][vs_dw(oct * 8 + i, kp)] = (uint)u0[i] | ((uint)u1[i] << 16);
    } else {
      *reinterpret_cast<bf16x8*>(&Ks[cur][kdst0]) = pre0;
      *reinterpret_cast<bf16x8*>(&Ks[cur][kdst1]) = pre1;
    }
    __syncthreads();   // single barrier per tile (double-buffered)

    // ---- issue next-tile global loads; latency hides under compute ----
    if (kt + 64 < 2048) {
      const bf16* nb = base + (size_t)(kt + 64) * 3072;
      if (vrole) {
        const bf16* v0p = nb + (size_t)(2 * kp) * 3072 + 2048 + oct * 8;
        pre0 = *reinterpret_cast<const bf16x8*>(v0p);
        pre1 = *reinterpret_cast<const bf16x8*>(v0p + 3072);
      } else {
        const bf16* kb = nb + 1024 + (size_t)kp * 3072 + oct * 8;
        pre0 = *reinterpret_cast<const bf16x8*>(kb);
        pre1 = *reinterpret_cast<const bf16x8*>(kb + (size_t)32 * 3072);
      }
    }

    // ---- S - m = K (Q*log2e)^T + nm : mfma with C-in = nm ----
    f32x4 s[4];
    __builtin_amdgcn_s_setprio(1);
    for (int n = 0; n < 4; n++) {
      int row = n * 16 + l15;
      int xr = row & 7;
      bf16x8 ak0 = *reinterpret_cast<const bf16x8*>(&Ks[cur][(row * 8 + (quad ^ xr)) * 8]);
      bf16x8 ak1 = *reinterpret_cast<const bf16x8*>(&Ks[cur][(row * 8 + ((4 + quad) ^ xr)) * 8]);
      f32x4 z = __builtin_amdgcn_mfma_f32_16x16x32_bf16(ak0, aq0, nm, 0, 0, 0);
      z = __builtin_amdgcn_mfma_f32_16x16x32_bf16(ak1, aq1, z, 0, 0, 0);
      s[n] = z;
    }
    __builtin_amdgcn_s_setprio(0);

    // ---- per-query online softmax on relative scores (s already - m) ----
    float mt = fmaxf(fmaxf(s[0][0], s[0][1]), s[0][2]);
    mt = fmaxf(fmaxf(mt, s[0][3]), s[1][0]);
    mt = fmaxf(fmaxf(mt, s[1][1]), s[1][2]);
    mt = fmaxf(fmaxf(mt, s[1][3]), s[2][0]);
    mt = fmaxf(fmaxf(mt, s[2][1]), s[2][2]);
    mt = fmaxf(fmaxf(mt, s[2][3]), s[3][0]);
    mt = fmaxf(fmaxf(mt, s[3][1]), s[3][2]);
    mt = fmaxf(mt, s[3][3]);

    // defer-max: rescale only when some lane's local max grew past +8.
    // (global_max <= m+8 iff ALL lanes' local relative maxes <= 8.)
    if (!__all(mt <= 8.0f)) {
      mt = fmaxf(mt, __shfl_xor(mt, 16, 64));
      mt = fmaxf(mt, __shfl_xor(mt, 32, 64));   // global relative max for l15
      mt = fmaxf(mt, 0.0f);                     // monotone m: shift >= 0
      float alpha = __builtin_amdgcn_exp2f(-mt);  // <= 1
      float v = nm[0] - mt;                      // new -m (replicated)
      nm[0] = v; nm[1] = v; nm[2] = v; nm[3] = v;
      float a0 = __shfl(alpha, quad * 4 + 0, 64);
      float a1 = __shfl(alpha, quad * 4 + 1, 64);
      float a2 = __shfl(alpha, quad * 4 + 2, 64);
      float a3 = __shfl(alpha, quad * 4 + 3, 64);
      l_acc[0] *= a0; l_acc[1] *= a1; l_acc[2] *= a2; l_acc[3] *= a3;
      for (int n = 0; n < 4; n++) {
        o[n][0] *= a0; o[n][1] *= a1; o[n][2] *= a2; o[n][3] *= a3;
      }
      for (int n = 0; n < 4; n++)
        for (int r = 0; r < 4; r++) s[n][r] -= mt;   // shift to new m
    }

    // P in PV A-fragment order directly (rho-permuted K rows); s is relative
    bf16x8 ap0, ap1;
    for (int r = 0; r < 4; r++) {
      ap0[r]     = (bf16)__builtin_amdgcn_exp2f(s[0][r]);
      ap0[4 + r] = (bf16)__builtin_amdgcn_exp2f(s[1][r]);
      ap1[r]     = (bf16)__builtin_amdgcn_exp2f(s[2][r]);
      ap1[4 + r] = (bf16)__builtin_amdgcn_exp2f(s[3][r]);
    }

    __builtin_amdgcn_s_setprio(1);
    // row-sum via ones-column (C-layout rows = queries quad*4+r)
    l_acc = __builtin_amdgcn_mfma_f32_16x16x32_bf16(ap0, bones, l_acc, 0, 0, 0);
    l_acc = __builtin_amdgcn_mfma_f32_16x16x32_bf16(ap1, bones, l_acc, 0, 0, 0);

    // O += P V  (V fragments from swizzled Vs)
    for (int n = 0; n < 4; n++) {
      int d = n * 16 + l15;
      uint4 u0 = *reinterpret_cast<const uint4*>(&Vs[cur][vs_dw(d, quad * 4)]);
      uint4 u1 = *reinterpret_cast<const uint4*>(&Vs[cur][vs_dw(d, 16 + quad * 4)]);
      bf16x8 bv0 = *reinterpret_cast<const bf16x8*>(&u0);
      bf16x8 bv1 = *reinterpret_cast<const bf16x8*>(&u1);
      o[n] = __builtin_amdgcn_mfma_f32_16x16x32_bf16(ap0, bv0, o[n], 0, 0, 0);
      o[n] = __builtin_amdgcn_mfma_f32_16x16x32_bf16(ap1, bv1, o[n], 0, 0, 0);
    }
    __builtin_amdgcn_s_setprio(0);
  }

  for (int r = 0; r < 4; r++) {
    float lv = __shfl(l_acc[r], quad * 16, 64);
    float inv = 1.0f / lv;
    int q = qt0 + wave * 16 + quad * 4 + r;
    bf16* orow = out + (size_t)(b * 2048 + q) * 1024 + h * 64;
    for (int n = 0; n < 4; n++) orow[n * 16 + l15] = (bf16)(o[n][r] * inv);
  }
}

// ---------------------------------------------------------------------------
// Launch
// ---------------------------------------------------------------------------
extern "C" void kernel_launch(void* const* d_in, const int* in_sizes, int n_in,
                              void* d_out, int out_size, void* d_ws, size_t ws_size,
                              hipStream_t stream) {
  const float* x = (const float*)d_in[0];       // [8192, 1024] fp32
  const float* w_qkv = (const float*)d_in[1];   // [1024, 3072] fp32
  const float* w_proj = (const float*)d_in[2];  // [1024, 1024] fp32
  float* out = (float*)d_out;                   // [8192, 1024] fp32

  bf16* ws = (bf16*)d_ws;
  bf16* x_bf = ws;                                   // [8192,1024]
  bf16* wqkvT = x_bf + (size_t)8192 * 1024;          // [3072,1024]
  bf16* wprojT = wqkvT + 3072 * 1024;                // [1024,1024]
  bf16* qkv = wprojT + 1024 * 1024;                  // [8192,3072]
  bf16* attn_out = qkv + (size_t)8192 * 3072;        // [8192,1024]

  cast_f32_bf16<<<4096, 256, 0, stream>>>(x, x_bf);
  transpose_f32_bf16<<<dim3(48, 16), 256, 0, stream>>>(w_qkv, wqkvT, 1024, 3072);
  transpose_f32_bf16<<<dim3(16, 16), 256, 0, stream>>>(w_proj, wprojT, 1024, 1024);
  gemm_lds<bf16><<<dim3(24, 64), 256, 0, stream>>>(x_bf, wqkvT, qkv, 8192, 3072, 1024);
  attn_kernel<<<dim3(64, 16), 512, 0, stream>>>(qkv, attn_out);
  gemm_lds<float><<<dim3(8, 64), 256, 0, stream>>>(attn_out, wprojT, out, 8192, 1024, 1024);
}